// Round 7
// baseline (300.235 us; speedup 1.0000x reference)
//
#include <hip/hip_runtime.h>

// Gate-level FP8 E4M3 adder circuit, replayed as integer bit ops.
// Each row = 8 float32 "bits" (sign | exp4 | man3, MSB first), values in {0.0,1.0}.
// 1.0f == 0x3F800000 -> bit = (u >> 23) & 1. Output bit b -> b ? 0x3F800000 : 0.
//
// R6: force deep MLP. R2/R4/R5 all kept only ~4 loads in flight per wave
// (VGPR 28-36: the scheduler sinks loads when pressure is low) and all landed
// at 79-81 us; R5's traffic cleanup moved bytes but not time -> latency/MLP
// limited, not bytes-limited. A single asm volatile fence consuming all 16
// loaded values forces all 16 nt dwordx4 loads to issue before any compute:
// 16 KB in flight per wave (4x), at ~80-100 VGPR (still >=6 waves/SIMD).

typedef unsigned int uint32x4 __attribute__((ext_vector_type(4)));

__device__ __forceinline__ unsigned bit_of(unsigned u) { return (u >> 23) & 1u; }
__device__ __forceinline__ unsigned f_of(unsigned b)   { return b ? 0x3F800000u : 0u; }

__device__ __forceinline__ void fp8_add_row(const uint32x4& a0, const uint32x4& a1,
                                            const uint32x4& b0, const uint32x4& b1,
                                            uint32x4& o0, uint32x4& o1)
{
    unsigned sa = bit_of(a0.x);
    unsigned ea = (bit_of(a0.y) << 3) | (bit_of(a0.z) << 2) | (bit_of(a0.w) << 1) | bit_of(a1.x);
    unsigned ma = (bit_of(a1.y) << 2) | (bit_of(a1.z) << 1) | bit_of(a1.w);
    unsigned sb = bit_of(b0.x);
    unsigned eb = (bit_of(b0.y) << 3) | (bit_of(b0.z) << 2) | (bit_of(b0.w) << 1) | bit_of(b1.x);
    unsigned mb = (bit_of(b1.y) << 2) | (bit_of(b1.z) << 1) | bit_of(b1.w);

    // comparator4 + OR(gt,eq): sel = (ea >= eb)
    unsigned sel = (ea >= eb) ? 1u : 0u;
    unsigned exp_l = sel ? ea : eb, exp_s = sel ? eb : ea;
    unsigned man_l = sel ? ma : mb, man_s = sel ? mb : ma;
    unsigned sign_l = sel ? sa : sb, sign_s = sel ? sb : sa;

    unsigned diff = (exp_l - exp_s) & 0xFu;        // 4-bit subtract, exact (l >= s)
    unsigned hid_l = exp_l ? 1u : 0u;
    unsigned hid_s = exp_s ? 1u : 0u;

    // 12-bit extended mantissas, MSB-first bit 11..0: [0, hid, man(3), 0*7]
    unsigned ext_l = (hid_l << 10) | (man_l << 7);
    unsigned ext_s = ((hid_s << 10) | (man_s << 7)) >> diff;

    unsigned same_sign = (sign_l == sign_s);
    // 12-bit ripple add/sub both wrap mod 4096 (carry/borrow-out dropped)
    unsigned mant = same_sign ? ((ext_l + ext_s) & 0xFFFu)
                              : ((ext_l - ext_s) & 0xFFFu);

    unsigned top8 = mant >> 4;                     // mant bits 11..4
    unsigned lzc = top8 ? (unsigned)(__clz((int)top8) - 24) : 7u;  // lzd8 -> 7 on zero
    unsigned norm = (top8 << lzc) & 0xFFu;         // barrel_left8

    unsigned exp_new = (exp_l - lzc + 1u) & 0xFu;  // subtract_bits + increment4, mod 16
    unsigned man_out = (norm >> 4) & 0x7u;         // norm[1:4] = bits 6..4

    o0.x = f_of(sign_l);
    o0.y = f_of((exp_new >> 3) & 1u);
    o0.z = f_of((exp_new >> 2) & 1u);
    o0.w = f_of((exp_new >> 1) & 1u);
    o1.x = f_of(exp_new & 1u);
    o1.y = f_of((man_out >> 2) & 1u);
    o1.z = f_of((man_out >> 1) & 1u);
    o1.w = f_of(man_out & 1u);
}

constexpr int RPT = 4;
constexpr int BLOCK = 256;
constexpr int ROWS_PER_BLOCK = BLOCK * RPT;

__global__ __launch_bounds__(BLOCK) void fp8_adder_fast(
    const uint32x4* __restrict__ A, const uint32x4* __restrict__ B,
    uint32x4* __restrict__ O)
{
    int base = blockIdx.x * ROWS_PER_BLOCK + threadIdx.x;

    uint32x4 a0[RPT], a1[RPT], b0[RPT], b1[RPT];
    #pragma unroll
    for (int k = 0; k < RPT; ++k) {
        int i = base + k * BLOCK;
        a0[k] = __builtin_nontemporal_load(&A[2 * i]);
        a1[k] = __builtin_nontemporal_load(&A[2 * i + 1]);
        b0[k] = __builtin_nontemporal_load(&B[2 * i]);
        b1[k] = __builtin_nontemporal_load(&B[2 * i + 1]);
    }

    // MLP fence: one volatile asm consuming every loaded value. All 16
    // global_load_dwordx4 must issue before anything after this point;
    // s_waitcnt for each value lands at its first use below, amortized.
    asm volatile(""
        : "+v"(a0[0]), "+v"(a0[1]), "+v"(a0[2]), "+v"(a0[3]),
          "+v"(a1[0]), "+v"(a1[1]), "+v"(a1[2]), "+v"(a1[3]),
          "+v"(b0[0]), "+v"(b0[1]), "+v"(b0[2]), "+v"(b0[3]),
          "+v"(b1[0]), "+v"(b1[1]), "+v"(b1[2]), "+v"(b1[3]));

    #pragma unroll
    for (int k = 0; k < RPT; ++k) {
        int i = base + k * BLOCK;
        uint32x4 o0, o1;
        fp8_add_row(a0[k], a1[k], b0[k], b1[k], o0, o1);
        __builtin_nontemporal_store(o0, &O[2 * i]);
        __builtin_nontemporal_store(o1, &O[2 * i + 1]);
    }
}

// Tail: bounds-checked, one row per thread.
__global__ __launch_bounds__(BLOCK) void fp8_adder_tail(
    const uint32x4* __restrict__ A, const uint32x4* __restrict__ B,
    uint32x4* __restrict__ O, int row0, int n_rows)
{
    int i = row0 + blockIdx.x * BLOCK + threadIdx.x;
    if (i >= n_rows) return;
    uint32x4 a0 = __builtin_nontemporal_load(&A[2 * i]);
    uint32x4 a1 = __builtin_nontemporal_load(&A[2 * i + 1]);
    uint32x4 b0 = __builtin_nontemporal_load(&B[2 * i]);
    uint32x4 b1 = __builtin_nontemporal_load(&B[2 * i + 1]);
    uint32x4 o0, o1;
    fp8_add_row(a0, a1, b0, b1, o0, o1);
    __builtin_nontemporal_store(o0, &O[2 * i]);
    __builtin_nontemporal_store(o1, &O[2 * i + 1]);
}

extern "C" void kernel_launch(void* const* d_in, const int* in_sizes, int n_in,
                              void* d_out, int out_size, void* d_ws, size_t ws_size,
                              hipStream_t stream) {
    const uint32x4* A = (const uint32x4*)d_in[0];
    const uint32x4* B = (const uint32x4*)d_in[1];
    uint32x4* O = (uint32x4*)d_out;
    int n_rows = in_sizes[0] / 8;

    int full_blocks = n_rows / ROWS_PER_BLOCK;
    int done_rows = full_blocks * ROWS_PER_BLOCK;
    int rem = n_rows - done_rows;

    if (full_blocks > 0)
        fp8_adder_fast<<<full_blocks, BLOCK, 0, stream>>>(A, B, O);
    if (rem > 0) {
        int tail_blocks = (rem + BLOCK - 1) / BLOCK;
        fp8_adder_tail<<<tail_blocks, BLOCK, 0, stream>>>(A, B, O, done_rows, n_rows);
    }
}

// Round 8
// 295.811 us; speedup vs baseline: 1.0150x; 1.0150x over previous
//
#include <hip/hip_runtime.h>

// Gate-level FP8 E4M3 adder circuit, replayed as integer bit ops.
// Each row = 8 float32 "bits" (sign | exp4 | man3, MSB first), values in {0.0,1.0}.
// 1.0f == 0x3F800000 -> bit = (u >> 23) & 1. Output bit b -> b ? 0x3F800000 : 0.
//
// R7: store-policy A/B vs R5 (single variable). R6 killed the MLP theory
// (forced 16-load burst: no gain). R2/R4/R5 all plateau at ~79 us / 3.5 TB/s
// regardless of access shape -> policy-limited. Both ~6.3-6.8 TB/s reference
// kernels (m13 copy, harness fill) use PLAIN stores: L2 aggregates full dirty
// lines, controller drains write-backs in bursts (minimal r/w turnaround).
// So: nt loads (keep input out of L2) + PLAIN stores (let L2 do its job).

typedef unsigned int uint32x4 __attribute__((ext_vector_type(4)));

__device__ __forceinline__ unsigned bit_of(unsigned u) { return (u >> 23) & 1u; }
__device__ __forceinline__ unsigned f_of(unsigned b)   { return b ? 0x3F800000u : 0u; }

// Bijective self-inverse swizzle on 16B-slot index m in [0,128):
// XOR low 3 bits with bits 3..5. Dense (m=lane) and stride-2 (m=2*lane(+1))
// phases both give all-distinct bank classes within every 8-lane group.
__device__ __forceinline__ int swz(int m) { return m ^ ((m >> 3) & 7); }

__device__ __forceinline__ void fp8_add_row(const uint32x4& a0, const uint32x4& a1,
                                            const uint32x4& b0, const uint32x4& b1,
                                            uint32x4& o0, uint32x4& o1)
{
    unsigned sa = bit_of(a0.x);
    unsigned ea = (bit_of(a0.y) << 3) | (bit_of(a0.z) << 2) | (bit_of(a0.w) << 1) | bit_of(a1.x);
    unsigned ma = (bit_of(a1.y) << 2) | (bit_of(a1.z) << 1) | bit_of(a1.w);
    unsigned sb = bit_of(b0.x);
    unsigned eb = (bit_of(b0.y) << 3) | (bit_of(b0.z) << 2) | (bit_of(b0.w) << 1) | bit_of(b1.x);
    unsigned mb = (bit_of(b1.y) << 2) | (bit_of(b1.z) << 1) | bit_of(b1.w);

    // comparator4 + OR(gt,eq): sel = (ea >= eb)
    unsigned sel = (ea >= eb) ? 1u : 0u;
    unsigned exp_l = sel ? ea : eb, exp_s = sel ? eb : ea;
    unsigned man_l = sel ? ma : mb, man_s = sel ? mb : ma;
    unsigned sign_l = sel ? sa : sb, sign_s = sel ? sb : sa;

    unsigned diff = (exp_l - exp_s) & 0xFu;        // 4-bit subtract, exact (l >= s)
    unsigned hid_l = exp_l ? 1u : 0u;
    unsigned hid_s = exp_s ? 1u : 0u;

    // 12-bit extended mantissas, MSB-first bit 11..0: [0, hid, man(3), 0*7]
    unsigned ext_l = (hid_l << 10) | (man_l << 7);
    unsigned ext_s = ((hid_s << 10) | (man_s << 7)) >> diff;

    unsigned same_sign = (sign_l == sign_s);
    // 12-bit ripple add/sub both wrap mod 4096 (carry/borrow-out dropped)
    unsigned mant = same_sign ? ((ext_l + ext_s) & 0xFFFu)
                              : ((ext_l - ext_s) & 0xFFFu);

    unsigned top8 = mant >> 4;                     // mant bits 11..4
    unsigned lzc = top8 ? (unsigned)(__clz((int)top8) - 24) : 7u;  // lzd8 -> 7 on zero
    unsigned norm = (top8 << lzc) & 0xFFu;         // barrel_left8

    unsigned exp_new = (exp_l - lzc + 1u) & 0xFu;  // subtract_bits + increment4, mod 16
    unsigned man_out = (norm >> 4) & 0x7u;         // norm[1:4] = bits 6..4

    o0.x = f_of(sign_l);
    o0.y = f_of((exp_new >> 3) & 1u);
    o0.z = f_of((exp_new >> 2) & 1u);
    o0.w = f_of((exp_new >> 1) & 1u);
    o1.x = f_of(exp_new & 1u);
    o1.y = f_of((man_out >> 2) & 1u);
    o1.z = f_of((man_out >> 1) & 1u);
    o1.w = f_of(man_out & 1u);
}

constexpr int RPT = 4;            // rounds per wave (64 rows each)
constexpr int BLOCK = 256;
constexpr int WAVES = BLOCK / 64;
constexpr int ROWS_PER_BLOCK = BLOCK * RPT;  // 1024

__global__ __launch_bounds__(BLOCK) void fp8_adder_fast(
    const uint32x4* __restrict__ A, const uint32x4* __restrict__ B,
    uint32x4* __restrict__ O)
{
    // Per-wave: 256 slots of 16B -> A words [0,128), B words [128,256).
    __shared__ uint32x4 sh[WAVES * 256];

    int lane = threadIdx.x & 63;
    int w = threadIdx.x >> 6;
    uint32x4* shW = &sh[w * 256];

    int rowBase = blockIdx.x * ROWS_PER_BLOCK + w * (64 * RPT);

    #pragma unroll
    for (int k = 0; k < RPT; ++k) {
        int WW = 2 * (rowBase + k * 64);   // word index of first A/B word this round

        // Dense, full-line nt loads: lane l gets word WW+l and WW+64+l.
        uint32x4 vA0 = __builtin_nontemporal_load(&A[WW + lane]);
        uint32x4 vA1 = __builtin_nontemporal_load(&A[WW + 64 + lane]);
        uint32x4 vB0 = __builtin_nontemporal_load(&B[WW + lane]);
        uint32x4 vB1 = __builtin_nontemporal_load(&B[WW + 64 + lane]);

        // Stage word m at slot swz(m) (intra-wave, no barrier needed).
        shW[swz(lane)]            = vA0;
        shW[swz(64 + lane)]       = vA1;
        shW[128 + swz(lane)]      = vB0;
        shW[128 + swz(64 + lane)] = vB1;

        // Lane l owns row rowBase + k*64 + l -> words 2l, 2l+1.
        uint32x4 a0 = shW[swz(2 * lane)];
        uint32x4 a1 = shW[swz(2 * lane + 1)];
        uint32x4 b0 = shW[128 + swz(2 * lane)];
        uint32x4 b1 = shW[128 + swz(2 * lane + 1)];

        uint32x4 o0, o1;
        fp8_add_row(a0, a1, b0, b1, o0, o1);

        // Deposit results (reuse A region), read back dense, store full-line.
        shW[swz(2 * lane)]     = o0;
        shW[swz(2 * lane + 1)] = o1;

        uint32x4 w0 = shW[swz(lane)];
        uint32x4 w1 = shW[swz(64 + lane)];
        // PLAIN stores (the single change vs R5): allow L2 write-allocate and
        // burst write-back instead of fine-grained nt writes at the controller.
        O[WW + lane]      = w0;
        O[WW + 64 + lane] = w1;
    }
}

// Tail: bounds-checked, one row per thread (general-case safety net).
__global__ __launch_bounds__(BLOCK) void fp8_adder_tail(
    const uint32x4* __restrict__ A, const uint32x4* __restrict__ B,
    uint32x4* __restrict__ O, int row0, int n_rows)
{
    int i = row0 + blockIdx.x * BLOCK + threadIdx.x;
    if (i >= n_rows) return;
    uint32x4 a0 = __builtin_nontemporal_load(&A[2 * i]);
    uint32x4 a1 = __builtin_nontemporal_load(&A[2 * i + 1]);
    uint32x4 b0 = __builtin_nontemporal_load(&B[2 * i]);
    uint32x4 b1 = __builtin_nontemporal_load(&B[2 * i + 1]);
    uint32x4 o0, o1;
    fp8_add_row(a0, a1, b0, b1, o0, o1);
    O[2 * i]     = o0;
    O[2 * i + 1] = o1;
}

extern "C" void kernel_launch(void* const* d_in, const int* in_sizes, int n_in,
                              void* d_out, int out_size, void* d_ws, size_t ws_size,
                              hipStream_t stream) {
    const uint32x4* A = (const uint32x4*)d_in[0];
    const uint32x4* B = (const uint32x4*)d_in[1];
    uint32x4* O = (uint32x4*)d_out;
    int n_rows = in_sizes[0] / 8;

    int full_blocks = n_rows / ROWS_PER_BLOCK;
    int done_rows = full_blocks * ROWS_PER_BLOCK;
    int rem = n_rows - done_rows;

    if (full_blocks > 0)
        fp8_adder_fast<<<full_blocks, BLOCK, 0, stream>>>(A, B, O);
    if (rem > 0) {
        int tail_blocks = (rem + BLOCK - 1) / BLOCK;
        fp8_adder_tail<<<tail_blocks, BLOCK, 0, stream>>>(A, B, O, done_rows, n_rows);
    }
}